// Round 1
// baseline (509.299 us; speedup 1.0000x reference)
//
#include <hip/hip_runtime.h>

// ---------------------------------------------------------------------------
// SelfAttentionLayer (talking-heads) on MI355X gfx950. Round 7.
// Attention v7 = 2-way j-split + 2 blocks/CU residency:
//   * grid 512 blocks (it, b, s) decoded so XCD = bid%8 = (b + 4s): each XCD's
//     K/V working set is 2 MB -> fits the 4 MB per-XCD L2.
//   * __launch_bounds__(1024, 8) caps waves at 64 unified regs so TWO 16-wave
//     blocks co-reside per CU (latency/barrier bubbles filled by TLP).
//     To fit: no cross-tile K prefetch (K loaded in two 16-reg halves/tile),
//     V loaded inline in PV, epilogue mix2 moved to a separate combine kernel.
//   * blocks write unnormalized partial U (f16) + partial l (f32); combine
//     kernel normalizes, applies mix2 (W2) + bsum, writes ob.
// GEMMs / LN / transpose unchanged from round 6.
// ---------------------------------------------------------------------------

typedef _Float16 f16x8 __attribute__((ext_vector_type(8)));
typedef _Float16 f16x4 __attribute__((ext_vector_type(4)));
typedef _Float16 f16x2 __attribute__((ext_vector_type(2)));
typedef float f32x4 __attribute__((ext_vector_type(4)));

#define B_ 4
#define N_ 1024
#define D_ 1024
#define H_ 16
#define DH_ 64
#define FF_ 4096
#define M_ (B_ * N_)

__device__ __forceinline__ float gelu_act(float x) {
  float z = 0.7978845608028654f * (x + 0.044715f * x * x * x);
  return x / (1.0f + __expf(-2.0f * z));
}

__device__ __forceinline__ void ld_lds16(const _Float16* g, _Float16* l) {
  __builtin_amdgcn_global_load_lds((const __attribute__((address_space(1))) void*)g,
                                   (__attribute__((address_space(3))) void*)l, 16, 0, 0);
}

__device__ __forceinline__ int swz8(int i) {
  return (((i >> 2) << 1) ^ (i & 3)) & 7;
}
// S/P plane addressing (v4/v5-proven): plane p stride 1032 f16, row i (64 f16),
// col j chunk-swizzled. mix1 u16 gathers, b64 writes, b128 PV reads <=2-way.
__device__ __forceinline__ int lds_off(int p, int i, int j) {
  int ch = ((j >> 3) ^ swz8(i) ^ ((p >> 2) << 1)) & 7;
  return p * 1032 + i * 64 + (ch << 3) + (j & 7);
}

// ---------------- fp32 -> fp16 cast (weights) ----------------
__global__ __launch_bounds__(256) void cast_f32_f16(const float* __restrict__ in,
                                                    _Float16* __restrict__ out, int n) {
  int i = (blockIdx.x * 256 + threadIdx.x) * 4;
  if (i >= n) return;
  float4 v = *(const float4*)(in + i);
  f16x4 o;
  o[0] = (_Float16)v.x; o[1] = (_Float16)v.y; o[2] = (_Float16)v.z; o[3] = (_Float16)v.w;
  *(f16x4*)(out + i) = o;
}

// ---------------- prep mix weights: f16 row-major copies ----------------
__global__ __launch_bounds__(256) void prep_w(const float* __restrict__ W1,
                                              const float* __restrict__ W2,
                                              _Float16* __restrict__ w1f,
                                              _Float16* __restrict__ w2f) {
  int t = threadIdx.x;
  w1f[t] = (_Float16)W1[t];
  w2f[t] = (_Float16)W2[t];
}

// ---------------- bsum[b][g*64+d] = b2[g] * sum_j V[b,g,j,d] ----------------
__global__ __launch_bounds__(256) void vsum_k(const _Float16* __restrict__ vt,
                                              const float* __restrict__ b2,
                                              float* __restrict__ bsum) {
  int g = blockIdx.x, b = blockIdx.y;
  int t = threadIdx.x;
  int d = t >> 2, seg = t & 3;
  const _Float16* row = vt + (size_t)((b * H_ + g) * DH_ + d) * N_ + seg * 256;
  float s = 0.f;
  #pragma unroll
  for (int k = 0; k < 32; k++) {
    f16x8 v = *(const f16x8*)(row + k * 8);
    #pragma unroll
    for (int e = 0; e < 8; e++) s += (float)v[e];
  }
  s += __shfl_xor(s, 1);
  s += __shfl_xor(s, 2);
  if (seg == 0) bsum[b * D_ + g * 64 + d] = b2[g] * s;
}

// ---------------- LayerNorm (row of 1024) -> fp16 ----------------
__global__ __launch_bounds__(256) void ln_f16(const float* __restrict__ x,
                                              const float* __restrict__ w,
                                              const float* __restrict__ b,
                                              _Float16* __restrict__ out) {
  int row = blockIdx.x;
  int tid = threadIdx.x;
  const float* xr = x + (size_t)row * D_;
  float4 v = *(const float4*)(xr + tid * 4);
  float s = v.x + v.y + v.z + v.w;
  float sq = v.x * v.x + v.y * v.y + v.z * v.z + v.w * v.w;
  #pragma unroll
  for (int off = 32; off > 0; off >>= 1) {
    s += __shfl_down(s, off);
    sq += __shfl_down(sq, off);
  }
  __shared__ float red[8];
  int wave = tid >> 6, lane = tid & 63;
  if (lane == 0) { red[wave] = s; red[4 + wave] = sq; }
  __syncthreads();
  float ts = red[0] + red[1] + red[2] + red[3];
  float tq = red[4] + red[5] + red[6] + red[7];
  float mean = ts * (1.0f / (float)D_);
  float var = tq * (1.0f / (float)D_) - mean * mean;
  float rs = rsqrtf(var + 1e-5f);
  float4 wv = *(const float4*)(w + tid * 4);
  float4 bv = *(const float4*)(b + tid * 4);
  f16x4 o;
  o[0] = (_Float16)((v.x - mean) * rs * wv.x + bv.x);
  o[1] = (_Float16)((v.y - mean) * rs * wv.y + bv.y);
  o[2] = (_Float16)((v.z - mean) * rs * wv.z + bv.z);
  o[3] = (_Float16)((v.w - mean) * rs * wv.w + bv.w);
  *(f16x4*)(out + (size_t)row * D_ + tid * 4) = o;
}

// ---------------- NT GEMM: C[M,N] = A[M,K] @ W[N,K]^T + bias ----------------
template <int EPI, int BN, int OCC>
__global__ __launch_bounds__(256, OCC) void gemm_nt(
    const _Float16* __restrict__ A, const _Float16* __restrict__ W,
    const float* __restrict__ bias, int M, int N, int K,
    _Float16* __restrict__ outB, float* __restrict__ outF,
    const float* __restrict__ res, const float* __restrict__ gamma) {
  __shared__ _Float16 As[128 * 64];
  __shared__ _Float16 Bs[BN * 64];
  int tid = threadIdx.x;
  int wave = tid >> 6, lane = tid & 63;
  int quad = lane >> 4, l16 = lane & 15;
  int wm = wave >> 1, wn = wave & 1;
  int m0 = blockIdx.y * 128, n0 = blockIdx.x * BN;
  int lrow = lane >> 3, lcol = (lane & 7) * 8;
  const int NI = (BN == 128) ? 4 : 2;
  const int WN = (BN == 128) ? 64 : 32;

  f32x4 zero = {0.f, 0.f, 0.f, 0.f};
  f32x4 acc[4][NI];
  #pragma unroll
  for (int i = 0; i < 4; i++)
    #pragma unroll
    for (int j = 0; j < NI; j++) acc[i][j] = zero;

  for (int k0 = 0; k0 < K; k0 += 64) {
    __syncthreads();
    #pragma unroll
    for (int c = 0; c < 4; c++) {
      int rb = c * 32 + wave * 8;
      ld_lds16(A + (size_t)(m0 + rb + lrow) * K + k0 + lcol, As + rb * 64);
      if (BN == 128 || c < 2)
        ld_lds16(W + (size_t)(n0 + rb + lrow) * K + k0 + lcol, Bs + rb * 64);
    }
    __syncthreads();
    #pragma unroll
    for (int ks = 0; ks < 2; ks++) {
      int kk = ks * 32 + quad * 8;
      f16x8 a[4], bfr[NI];
      #pragma unroll
      for (int i = 0; i < 4; i++) a[i] = *(const f16x8*)(As + (wm * 64 + i * 16 + l16) * 64 + kk);
      #pragma unroll
      for (int i = 0; i < NI; i++) bfr[i] = *(const f16x8*)(Bs + (wn * WN + i * 16 + l16) * 64 + kk);
      #pragma unroll
      for (int mi = 0; mi < 4; mi++)
        #pragma unroll
        for (int ni = 0; ni < NI; ni++)
          acc[mi][ni] = __builtin_amdgcn_mfma_f32_16x16x32_f16(a[mi], bfr[ni], acc[mi][ni], 0, 0, 0);
    }
  }

  #pragma unroll
  for (int mi = 0; mi < 4; mi++) {
    int grow_base = m0 + wm * 64 + mi * 16 + quad * 4;
    #pragma unroll
    for (int ni = 0; ni < NI; ni++) {
      int gcol = n0 + wn * WN + ni * 16 + l16;
      float bb = bias[gcol];
      float gm = (EPI == 1) ? gamma[gcol] : 0.f;
      #pragma unroll
      for (int r = 0; r < 4; r++) {
        size_t oi = (size_t)(grow_base + r) * N + gcol;
        float c = acc[mi][ni][r] + bb;
        if (EPI == 0) {
          outB[oi] = (_Float16)c;
        } else if (EPI == 1) {
          outF[oi] = res[oi] + gm * c;
        } else {
          outB[oi] = (_Float16)gelu_act(c);
        }
      }
    }
  }
}

// ---------------- V transpose: vt[b][h][d][j] ----------------
__global__ __launch_bounds__(256) void transpose_v(const _Float16* __restrict__ qkv,
                                                   _Float16* __restrict__ vt) {
  int jt = blockIdx.x;
  int h = blockIdx.y;
  int b = blockIdx.z;
  __shared__ _Float16 tl[64][68];
  int tid = threadIdx.x;
  int j0 = jt * 64;
  #pragma unroll
  for (int k = 0; k < 16; k++) {
    int idx = k * 256 + tid;
    int jr = idx >> 6, dc = idx & 63;
    tl[jr][dc] = qkv[(size_t)(b * N_ + j0 + jr) * (3 * D_) + 2 * D_ + h * 64 + dc];
  }
  __syncthreads();
  #pragma unroll
  for (int k = 0; k < 16; k++) {
    int idx = k * 256 + tid;
    int dr = idx >> 6, jc = idx & 63;
    vt[(size_t)((b * H_ + h) * DH_ + dr) * N_ + j0 + jc] = tl[jc][dr];
  }
}

// ---------------- Talking-heads attention, v7: 2-way j-split ----------------
// 1-D grid 512: b = bid&3, s = (bid>>2)&1, i-tile = bid>>3. XCD = bid%8 =
// b+4s, so each XCD's K/V working set (one (b, j-half)) is 2 MB -> L2-hot.
// 16 waves; wave meaning: computeS: head h=wave; mix1: row i=wave;
// PV: mixed-head e=wave. Writes partial U (f16) and partial l (f32).
__global__ __launch_bounds__(1024, 8) void attn_th(
    const _Float16* __restrict__ qkv, const _Float16* __restrict__ vt,
    const _Float16* __restrict__ w1f, const float* __restrict__ b1f,
    _Float16* __restrict__ Up, float* __restrict__ lp) {
  __shared__ __align__(16) _Float16 SP[2 * 16512];  // S planes | P planes
  _Float16* Sp = SP;
  _Float16* Pp = SP + 16512;

  const int tid = threadIdx.x;
  const int wave = tid >> 6;
  const int lane = tid & 63;
  const int quad = lane >> 4, l16 = lane & 15;
  const int bid = blockIdx.x;
  const int b = bid & 3;
  const int s = (bid >> 2) & 1;
  const int i0 = (bid >> 3) << 4;
  const size_t bN = (size_t)b * N_;
  const f32x4 zero = {0.f, 0.f, 0.f, 0.f};

  // Q fragments (head=wave), pre-scaled by DH^-1/2 = 0.125 (exact in f16)
  f16x8 qf[2];
  #pragma unroll
  for (int ks = 0; ks < 2; ks++) {
    f16x8 q = *(const f16x8*)(qkv + (bN + i0 + l16) * 3072 + wave * 64 + ks * 32 + quad * 8);
    #pragma unroll
    for (int e = 0; e < 8; e++) q[e] = q[e] * (_Float16)0.125f;
    qf[ks] = q;
  }
  // W1 B-fragment: B[k=h][n=e] = W1[e][h]; bias applied post-MFMA (reg thrift)
  f16x4 w1a = *(const f16x4*)(w1f + l16 * 16 + quad * 4);
  const float b1v = b1f[l16];

  const _Float16* kbase = qkv + (bN + l16) * 3072 + 1024 + wave * 64 + quad * 8;
  const _Float16* vbase = vt + (size_t)((b * H_ + wave) * DH_ + l16) * N_ + quad * 8;

  f32x4 uacc[4];
  #pragma unroll
  for (int nt = 0; nt < 4; nt++) uacc[nt] = zero;
  float lacc = 0.f;

  const int sbase = s << 9;  // 512-key half

  for (int t = 0; t < 8; t++) {
    const int j0 = sbase + t * 64;
    // ---- S = (QK^T)^T for head h=wave, two jb-pair halves (<=16 live K regs)
    #pragma unroll
    for (int half = 0; half < 2; half++) {
      f16x8 kk[2][2];
      #pragma unroll
      for (int jb = 0; jb < 2; jb++) {
        const _Float16* kb = kbase + (size_t)(j0 + (half * 2 + jb) * 16) * 3072;
        kk[jb][0] = *(const f16x8*)kb;
        kk[jb][1] = *(const f16x8*)(kb + 32);
      }
      #pragma unroll
      for (int jb = 0; jb < 2; jb++) {
        f32x4 sr = __builtin_amdgcn_mfma_f32_16x16x32_f16(kk[jb][0], qf[0], zero, 0, 0, 0);
        sr = __builtin_amdgcn_mfma_f32_16x16x32_f16(kk[jb][1], qf[1], sr, 0, 0, 0);
        f16x4 sv;
        #pragma unroll
        for (int r = 0; r < 4; r++) sv[r] = (_Float16)sr[r];
        *(f16x4*)(Sp + lds_off(wave, l16, (half * 2 + jb) * 16 + quad * 4)) = sv;
      }
    }
    __syncthreads();
    // ---- mix1 (row i=wave) -> exp (unnormalized) -> P planes + l accumulate
    #pragma unroll
    for (int cg = 0; cg < 4; cg++) {
      f16x4 sf;
      #pragma unroll
      for (int t4 = 0; t4 < 4; t4++)
        sf[t4] = Sp[lds_off(quad * 4 + t4, wave, cg * 16 + l16)];
      f32x4 a = __builtin_amdgcn_mfma_f32_16x16x16f16(sf, w1a, zero, 0, 0, 0);
      f16x4 pv;
      #pragma unroll
      for (int r = 0; r < 4; r++) {
        float e = __expf(a[r] + b1v);
        lacc += e;
        pv[r] = (_Float16)e;
      }
      *(f16x4*)(Pp + lds_off(l16, wave, cg * 16 + quad * 4)) = pv;
    }
    __syncthreads();
    // ---- PV: U_e += V @ P_e^T (e=wave): C[m=d][n=i]; V loaded inline,
    // latency hidden by the co-resident second block (TLP, not prefetch regs)
    f16x8 pf0 = *(const f16x8*)(Pp + lds_off(wave, l16, quad * 8));
    f16x8 pf1 = *(const f16x8*)(Pp + lds_off(wave, l16, 32 + quad * 8));
    #pragma unroll
    for (int nt = 0; nt < 4; nt++) {
      f16x8 v0 = *(const f16x8*)(vbase + (size_t)(nt * 16) * N_ + j0);
      uacc[nt] = __builtin_amdgcn_mfma_f32_16x16x32_f16(v0, pf0, uacc[nt], 0, 0, 0);
    }
    #pragma unroll
    for (int nt = 0; nt < 4; nt++) {
      f16x8 v1 = *(const f16x8*)(vbase + (size_t)(nt * 16) * N_ + j0 + 32);
      uacc[nt] = __builtin_amdgcn_mfma_f32_16x16x32_f16(v1, pf1, uacc[nt], 0, 0, 0);
    }
    // no barrier: next computeS writes S planes (disjoint from P); mix1(t+1)
    // writes P only after the next barrier.
  }

  // ---- epilogue: partial l (per e=l16, i=wave) + partial U to global ----
  lacc += __shfl_xor(lacc, 16);
  lacc += __shfl_xor(lacc, 32);
  if (quad == 0) lp[(((size_t)s * B_ + b) * H_ + l16) * N_ + i0 + wave] = lacc;
  const size_t ub = ((((size_t)s * B_ + b) * H_ + wave) * N_ + i0 + l16) * 64;
  #pragma unroll
  for (int nt = 0; nt < 4; nt++) {
    f16x4 u;
    #pragma unroll
    for (int r = 0; r < 4; r++) u[r] = (_Float16)uacc[nt][r];
    *(f16x4*)(Up + ub + nt * 16 + quad * 4) = u;
  }
}

// ---------------- combine: Un=(U0+U1)/(l0+l1); ob = W2@Un + bsum ----------------
// grid (64 i-tiles, 4 b), 256 thr. Thread (il=t>>4, dg=(t&15)*4) computes all
// 16 output heads g for its (i, d-chunk): 1024 f32 FMA + 32x8B coalesced loads.
__global__ __launch_bounds__(256) void attn_combine(
    const _Float16* __restrict__ Up, const float* __restrict__ lp,
    const _Float16* __restrict__ w2f, const float* __restrict__ bsum,
    _Float16* __restrict__ ob) {
  const int i0 = blockIdx.x * 16;
  const int b = blockIdx.y;
  const int t = threadIdx.x;
  __shared__ float w2s[256];
  __shared__ float linv[16][17];
  {
    int e = t >> 4, il = t & 15;
    float l0 = lp[((size_t)(0 * B_ + b) * H_ + e) * N_ + i0 + il];
    float l1 = lp[((size_t)(1 * B_ + b) * H_ + e) * N_ + i0 + il];
    linv[e][il] = 1.0f / (l0 + l1);
    w2s[t] = (float)w2f[t];
  }
  __syncthreads();
  const int il = t >> 4, dg = (t & 15) * 4;
  const size_t s1off = (size_t)B_ * H_ * N_ * 64;
  float o[16][4];
  #pragma unroll
  for (int g = 0; g < 16; g++)
    #pragma unroll
    for (int r = 0; r < 4; r++) o[g][r] = 0.f;
  for (int e = 0; e < 16; e++) {
    size_t ubr = (((size_t)b * H_ + e) * N_ + i0 + il) * 64 + dg;
    f16x4 u0 = *(const f16x4*)(Up + ubr);
    f16x4 u1 = *(const f16x4*)(Up + s1off + ubr);
    float li = linv[e][il];
    float un[4];
    #pragma unroll
    for (int r = 0; r < 4; r++) un[r] = ((float)u0[r] + (float)u1[r]) * li;
    #pragma unroll
    for (int g = 0; g < 16; g++) {
      float w = w2s[g * 16 + e];
      #pragma unroll
      for (int r = 0; r < 4; r++) o[g][r] += w * un[r];
    }
  }
  const size_t rowbase = ((size_t)b * N_ + i0 + il) * D_;
  #pragma unroll
  for (int g = 0; g < 16; g++) {
    f32x4 bs = *(const f32x4*)(bsum + b * D_ + g * 64 + dg);
    f16x4 ov;
    #pragma unroll
    for (int r = 0; r < 4; r++) ov[r] = (_Float16)(o[g][r] + bs[r]);
    *(f16x4*)(ob + rowbase + g * 64 + dg) = ov;
  }
}

// ---------------------------------------------------------------------------
extern "C" void kernel_launch(void* const* d_in, const int* in_sizes, int n_in,
                              void* d_out, int out_size, void* d_ws, size_t ws_size,
                              hipStream_t stream) {
  const float* x      = (const float*)d_in[0];
  const float* ln1_w  = (const float*)d_in[1];
  const float* ln1_b  = (const float*)d_in[2];
  const float* qkv_w  = (const float*)d_in[3];
  const float* qkv_b  = (const float*)d_in[4];
  const float* plw    = (const float*)d_in[5];
  const float* plb    = (const float*)d_in[6];
  const float* pww    = (const float*)d_in[7];
  const float* pwb    = (const float*)d_in[8];
  const float* out_w  = (const float*)d_in[9];
  const float* out_b  = (const float*)d_in[10];
  const float* gamma1 = (const float*)d_in[11];
  const float* ln2_w  = (const float*)d_in[12];
  const float* ln2_b  = (const float*)d_in[13];
  const float* fc1_w  = (const float*)d_in[14];
  const float* fc1_b  = (const float*)d_in[15];
  const float* fc2_w  = (const float*)d_in[16];
  const float* fc2_b  = (const float*)d_in[17];
  const float* gamma2 = (const float*)d_in[18];
  float* out = (float*)d_out;

  char* ws = (char*)d_ws;
  _Float16* wq   = (_Float16*)(ws + 0);          // 6291456 B
  _Float16* wo   = (_Float16*)(ws + 6291456);    // 2097152 B
  _Float16* wf1  = (_Float16*)(ws + 8388608);    // 8388608 B (hosts mix tables during attn)
  _Float16* wf2  = (_Float16*)(ws + 16777216);   // 8388608 B (hosts lp during attn)
  float*    x1   = (float*)   (ws + 25165824);   // 16777216 B (hosts Up during attn)
  _Float16* ob   = (_Float16*)(ws + 41943040);   // 8388608 B
  _Float16* hb   = (_Float16*)(ws + 50331648);   // 8388608 B
  _Float16* qkvb = (_Float16*)(ws + 58720256);   // 25165824 B
  _Float16* vtb  = (_Float16*)(ws + 83886080);   // 8388608 B
  _Float16* fb   = (_Float16*)(ws + 58720256);   // 33554432 B, aliases qkvb+vtb (dead by then)
  _Float16* w1f  = (_Float16*)(ws + 8388608);          // 512 B
  _Float16* w2f  = (_Float16*)(ws + 8388608 + 512);    // 512 B
  float*    bsum = (float*)   (ws + 8388608 + 1024);   // 16384 B
  float*    lp   = (float*)   (ws + 16777216);         // 524288 B (aliases wf2, dead until fc2 cast)
  _Float16* Up   = (_Float16*)(ws + 25165824);         // 16777216 B (aliases x1, dead until out-proj)
  if (ws_size < 92274688) return;

  cast_f32_f16<<<3072 * 1024 / 1024, 256, 0, stream>>>(qkv_w, wq, 3072 * 1024);
  cast_f32_f16<<<1024 * 1024 / 1024, 256, 0, stream>>>(out_w, wo, 1024 * 1024);
  prep_w<<<1, 256, 0, stream>>>(plw, pww, w1f, w2f);

  ln_f16<<<4096, 256, 0, stream>>>(x, ln1_w, ln1_b, hb);
  gemm_nt<0, 128, 3><<<dim3(24, 32), 256, 0, stream>>>(hb, wq, qkv_b, M_, 3 * D_, D_, qkvb, nullptr, nullptr, nullptr);
  transpose_v<<<dim3(16, 16, 4), 256, 0, stream>>>(qkvb, vtb);
  vsum_k<<<dim3(16, 4), 256, 0, stream>>>(vtb, pwb, bsum);
  attn_th<<<512, 1024, 0, stream>>>(qkvb, vtb, w1f, plb, Up, lp);
  attn_combine<<<dim3(64, 4), 256, 0, stream>>>(Up, lp, w2f, bsum, ob);
  gemm_nt<1, 64, 4><<<dim3(16, 32), 256, 0, stream>>>(ob, wo, out_b, M_, D_, D_, nullptr, x1, x, gamma1);

  cast_f32_f16<<<4096 * 1024 / 1024, 256, 0, stream>>>(fc1_w, wf1, 4096 * 1024);
  cast_f32_f16<<<4096 * 1024 / 1024, 256, 0, stream>>>(fc2_w, wf2, 4096 * 1024);

  ln_f16<<<4096, 256, 0, stream>>>(x1, ln2_w, ln2_b, hb);
  gemm_nt<2, 128, 3><<<dim3(32, 32), 256, 0, stream>>>(hb, wf1, fc1_b, M_, FF_, D_, fb, nullptr, nullptr, nullptr);
  gemm_nt<1, 64, 4><<<dim3(16, 32), 256, 0, stream>>>(fb, wf2, fc2_b, M_, D_, FF_, nullptr, out, x1, gamma2);
}

// Round 2
// 490.552 us; speedup vs baseline: 1.0382x; 1.0382x over previous
//
#include <hip/hip_runtime.h>

// ---------------------------------------------------------------------------
// SelfAttentionLayer (talking-heads) on MI355X gfx950. Round 8.
// Attention v8 = round-6 structure (1 block/CU, 16 waves, register prefetch)
// with the vmcnt(0) barrier drain REMOVED:
//   * per-tile barriers are raw s_barrier with lgkmcnt(0)-only drain (LDS
//     visibility). Prefetched K(t+1)/V(t) global->reg loads stay in flight
//     across the barriers; their latency hides under S/mix1/PV compute.
//   * V tile fully prefetched at tile start (vreg[2][4]) - round 6 loaded the
//     second half inline in PV (exposed L2 latency).
//   * XCD-aware block decode (b = bid&3): blocks sharing a batch map to the
//     same XCD -> K/V working set 4 MB -> L2-resident (round-7-proven).
// GEMMs / LN / transpose / vsum unchanged from round 6.
// ---------------------------------------------------------------------------

typedef _Float16 f16x8 __attribute__((ext_vector_type(8)));
typedef _Float16 f16x4 __attribute__((ext_vector_type(4)));
typedef _Float16 f16x2 __attribute__((ext_vector_type(2)));
typedef float f32x4 __attribute__((ext_vector_type(4)));

#define B_ 4
#define N_ 1024
#define D_ 1024
#define H_ 16
#define DH_ 64
#define FF_ 4096
#define M_ (B_ * N_)

// LDS-visibility barrier WITHOUT vmcnt drain: global loads stay in flight.
// sched_barrier(0) fences pin LDS ops / loads on their side (rule #18).
#define BARRIER_LDS()                                    \
  do {                                                   \
    __builtin_amdgcn_sched_barrier(0);                   \
    asm volatile("s_waitcnt lgkmcnt(0)" ::: "memory");   \
    __builtin_amdgcn_s_barrier();                        \
    __builtin_amdgcn_sched_barrier(0);                   \
  } while (0)

__device__ __forceinline__ float gelu_act(float x) {
  float z = 0.7978845608028654f * (x + 0.044715f * x * x * x);
  return x / (1.0f + __expf(-2.0f * z));
}

__device__ __forceinline__ void ld_lds16(const _Float16* g, _Float16* l) {
  __builtin_amdgcn_global_load_lds((const __attribute__((address_space(1))) void*)g,
                                   (__attribute__((address_space(3))) void*)l, 16, 0, 0);
}

__device__ __forceinline__ int swz8(int i) {
  return (((i >> 2) << 1) ^ (i & 3)) & 7;
}
// S/P plane addressing (v4/v5-proven): plane p stride 1032 f16, row i (64 f16),
// col j chunk-swizzled. mix1 u16 gathers, b64 writes, b128 PV reads <=2-way.
__device__ __forceinline__ int lds_off(int p, int i, int j) {
  int ch = ((j >> 3) ^ swz8(i) ^ ((p >> 2) << 1)) & 7;
  return p * 1032 + i * 64 + (ch << 3) + (j & 7);
}

// ---------------- fp32 -> fp16 cast (weights) ----------------
__global__ __launch_bounds__(256) void cast_f32_f16(const float* __restrict__ in,
                                                    _Float16* __restrict__ out, int n) {
  int i = (blockIdx.x * 256 + threadIdx.x) * 4;
  if (i >= n) return;
  float4 v = *(const float4*)(in + i);
  f16x4 o;
  o[0] = (_Float16)v.x; o[1] = (_Float16)v.y; o[2] = (_Float16)v.z; o[3] = (_Float16)v.w;
  *(f16x4*)(out + i) = o;
}

// ---------------- prep mix weights: f16 row-major copies ----------------
__global__ __launch_bounds__(256) void prep_w(const float* __restrict__ W1,
                                              const float* __restrict__ W2,
                                              _Float16* __restrict__ w1f,
                                              _Float16* __restrict__ w2f) {
  int t = threadIdx.x;
  w1f[t] = (_Float16)W1[t];
  w2f[t] = (_Float16)W2[t];
}

// ---------------- bsum[b][g*64+d] = b2[g] * sum_j V[b,g,j,d] ----------------
__global__ __launch_bounds__(256) void vsum_k(const _Float16* __restrict__ vt,
                                              const float* __restrict__ b2,
                                              float* __restrict__ bsum) {
  int g = blockIdx.x, b = blockIdx.y;
  int t = threadIdx.x;
  int d = t >> 2, seg = t & 3;
  const _Float16* row = vt + (size_t)((b * H_ + g) * DH_ + d) * N_ + seg * 256;
  float s = 0.f;
  #pragma unroll
  for (int k = 0; k < 32; k++) {
    f16x8 v = *(const f16x8*)(row + k * 8);
    #pragma unroll
    for (int e = 0; e < 8; e++) s += (float)v[e];
  }
  s += __shfl_xor(s, 1);
  s += __shfl_xor(s, 2);
  if (seg == 0) bsum[b * D_ + g * 64 + d] = b2[g] * s;
}

// ---------------- LayerNorm (row of 1024) -> fp16 ----------------
__global__ __launch_bounds__(256) void ln_f16(const float* __restrict__ x,
                                              const float* __restrict__ w,
                                              const float* __restrict__ b,
                                              _Float16* __restrict__ out) {
  int row = blockIdx.x;
  int tid = threadIdx.x;
  const float* xr = x + (size_t)row * D_;
  float4 v = *(const float4*)(xr + tid * 4);
  float s = v.x + v.y + v.z + v.w;
  float sq = v.x * v.x + v.y * v.y + v.z * v.z + v.w * v.w;
  #pragma unroll
  for (int off = 32; off > 0; off >>= 1) {
    s += __shfl_down(s, off);
    sq += __shfl_down(sq, off);
  }
  __shared__ float red[8];
  int wave = tid >> 6, lane = tid & 63;
  if (lane == 0) { red[wave] = s; red[4 + wave] = sq; }
  __syncthreads();
  float ts = red[0] + red[1] + red[2] + red[3];
  float tq = red[4] + red[5] + red[6] + red[7];
  float mean = ts * (1.0f / (float)D_);
  float var = tq * (1.0f / (float)D_) - mean * mean;
  float rs = rsqrtf(var + 1e-5f);
  float4 wv = *(const float4*)(w + tid * 4);
  float4 bv = *(const float4*)(b + tid * 4);
  f16x4 o;
  o[0] = (_Float16)((v.x - mean) * rs * wv.x + bv.x);
  o[1] = (_Float16)((v.y - mean) * rs * wv.y + bv.y);
  o[2] = (_Float16)((v.z - mean) * rs * wv.z + bv.z);
  o[3] = (_Float16)((v.w - mean) * rs * wv.w + bv.w);
  *(f16x4*)(out + (size_t)row * D_ + tid * 4) = o;
}

// ---------------- NT GEMM: C[M,N] = A[M,K] @ W[N,K]^T + bias ----------------
template <int EPI, int BN, int OCC>
__global__ __launch_bounds__(256, OCC) void gemm_nt(
    const _Float16* __restrict__ A, const _Float16* __restrict__ W,
    const float* __restrict__ bias, int M, int N, int K,
    _Float16* __restrict__ outB, float* __restrict__ outF,
    const float* __restrict__ res, const float* __restrict__ gamma) {
  __shared__ _Float16 As[128 * 64];
  __shared__ _Float16 Bs[BN * 64];
  int tid = threadIdx.x;
  int wave = tid >> 6, lane = tid & 63;
  int quad = lane >> 4, l16 = lane & 15;
  int wm = wave >> 1, wn = wave & 1;
  int m0 = blockIdx.y * 128, n0 = blockIdx.x * BN;
  int lrow = lane >> 3, lcol = (lane & 7) * 8;
  const int NI = (BN == 128) ? 4 : 2;
  const int WN = (BN == 128) ? 64 : 32;

  f32x4 zero = {0.f, 0.f, 0.f, 0.f};
  f32x4 acc[4][NI];
  #pragma unroll
  for (int i = 0; i < 4; i++)
    #pragma unroll
    for (int j = 0; j < NI; j++) acc[i][j] = zero;

  for (int k0 = 0; k0 < K; k0 += 64) {
    __syncthreads();
    #pragma unroll
    for (int c = 0; c < 4; c++) {
      int rb = c * 32 + wave * 8;
      ld_lds16(A + (size_t)(m0 + rb + lrow) * K + k0 + lcol, As + rb * 64);
      if (BN == 128 || c < 2)
        ld_lds16(W + (size_t)(n0 + rb + lrow) * K + k0 + lcol, Bs + rb * 64);
    }
    __syncthreads();
    #pragma unroll
    for (int ks = 0; ks < 2; ks++) {
      int kk = ks * 32 + quad * 8;
      f16x8 a[4], bfr[NI];
      #pragma unroll
      for (int i = 0; i < 4; i++) a[i] = *(const f16x8*)(As + (wm * 64 + i * 16 + l16) * 64 + kk);
      #pragma unroll
      for (int i = 0; i < NI; i++) bfr[i] = *(const f16x8*)(Bs + (wn * WN + i * 16 + l16) * 64 + kk);
      #pragma unroll
      for (int mi = 0; mi < 4; mi++)
        #pragma unroll
        for (int ni = 0; ni < NI; ni++)
          acc[mi][ni] = __builtin_amdgcn_mfma_f32_16x16x32_f16(a[mi], bfr[ni], acc[mi][ni], 0, 0, 0);
    }
  }

  #pragma unroll
  for (int mi = 0; mi < 4; mi++) {
    int grow_base = m0 + wm * 64 + mi * 16 + quad * 4;
    #pragma unroll
    for (int ni = 0; ni < NI; ni++) {
      int gcol = n0 + wn * WN + ni * 16 + l16;
      float bb = bias[gcol];
      float gm = (EPI == 1) ? gamma[gcol] : 0.f;
      #pragma unroll
      for (int r = 0; r < 4; r++) {
        size_t oi = (size_t)(grow_base + r) * N + gcol;
        float c = acc[mi][ni][r] + bb;
        if (EPI == 0) {
          outB[oi] = (_Float16)c;
        } else if (EPI == 1) {
          outF[oi] = res[oi] + gm * c;
        } else {
          outB[oi] = (_Float16)gelu_act(c);
        }
      }
    }
  }
}

// ---------------- V transpose: vt[b][h][d][j] ----------------
__global__ __launch_bounds__(256) void transpose_v(const _Float16* __restrict__ qkv,
                                                   _Float16* __restrict__ vt) {
  int jt = blockIdx.x;
  int h = blockIdx.y;
  int b = blockIdx.z;
  __shared__ _Float16 tl[64][68];
  int tid = threadIdx.x;
  int j0 = jt * 64;
  #pragma unroll
  for (int k = 0; k < 16; k++) {
    int idx = k * 256 + tid;
    int jr = idx >> 6, dc = idx & 63;
    tl[jr][dc] = qkv[(size_t)(b * N_ + j0 + jr) * (3 * D_) + 2 * D_ + h * 64 + dc];
  }
  __syncthreads();
  #pragma unroll
  for (int k = 0; k < 16; k++) {
    int idx = k * 256 + tid;
    int dr = idx >> 6, jc = idx & 63;
    vt[(size_t)((b * H_ + h) * DH_ + dr) * N_ + j0 + jc] = tl[jc][dr];
  }
}

// ---------------- Talking-heads attention, v8 ----------------
// grid 256 (bid: b = bid&3 -> XCD = bid%8 pairs (b, it&1); i-tile = bid>>2),
// 1024 thr = 16 waves. Wave index means:
// computeS: head h=wave; mix1: row i=wave; PV: mixed-head e=wave;
// epilogue mix2/store: row i=wave.
__global__ __launch_bounds__(1024, 4) void attn_th(
    const _Float16* __restrict__ qkv, const _Float16* __restrict__ vt,
    const _Float16* __restrict__ w1f, const _Float16* __restrict__ w2f,
    const float* __restrict__ b1f, const float* __restrict__ bsum,
    _Float16* __restrict__ ob) {
  __shared__ __align__(16) _Float16 SP[2 * 16512];  // S planes | P planes
  __shared__ float lsum[272];                       // [e][i] + pad (stride 17)
  _Float16* Sp = SP;
  _Float16* Pp = SP + 16512;

  const int tid = threadIdx.x;
  const int wave = tid >> 6;
  const int lane = tid & 63;
  const int quad = lane >> 4, l16 = lane & 15;
  const int bid = blockIdx.x;
  const int b = bid & 3;
  const int i0 = (bid >> 2) << 4;
  const size_t bN = (size_t)b * N_;
  const f32x4 zero = {0.f, 0.f, 0.f, 0.f};

  // Q fragments (head=wave), pre-scaled by DH^-1/2 = 0.125 (exact in f16)
  f16x8 qf[2];
  #pragma unroll
  for (int ks = 0; ks < 2; ks++) {
    f16x8 q = *(const f16x8*)(qkv + (bN + i0 + l16) * 3072 + wave * 64 + ks * 32 + quad * 8);
    #pragma unroll
    for (int e = 0; e < 8; e++) q[e] = q[e] * (_Float16)0.125f;
    qf[ks] = q;
  }
  // W1 B-fragment: B[k=h][n=e] = W1[e][h]
  f16x4 w1a = *(const f16x4*)(w1f + l16 * 16 + quad * 4);
  float b1v = b1f[l16];
  f32x4 b1i = {b1v, b1v, b1v, b1v};

  const _Float16* kbase = qkv + (bN + l16) * 3072 + 1024 + wave * 64 + quad * 8;
  const _Float16* vbase = vt + (size_t)((b * H_ + wave) * DH_ + l16) * N_ + quad * 8;

  f32x4 uacc[4];
  #pragma unroll
  for (int nt = 0; nt < 4; nt++) uacc[nt] = zero;
  float lacc = 0.f;

  // K fragments for the current tile (reloaded in place each iteration)
  f16x8 kcur[4][2];
  auto loadK = [&](int j0) {
    #pragma unroll
    for (int jb = 0; jb < 4; jb++) {
      const _Float16* kb = kbase + (size_t)(j0 + jb * 16) * 3072;
      kcur[jb][0] = *(const f16x8*)kb;
      kcur[jb][1] = *(const f16x8*)(kb + 32);
    }
  };
  loadK(0);

  f16x8 vreg[2][4];  // full V tile, prefetched at tile start

  for (int t = 0; t < 16; t++) {
    const int j0 = t * 64;
    // ---- issue this tile's V loads first: latency covered by S + bar1 + mix1
    #pragma unroll
    for (int h = 0; h < 2; h++)
      #pragma unroll
      for (int nt = 0; nt < 4; nt++)
        vreg[h][nt] = *(const f16x8*)(vbase + (size_t)(nt * 16) * N_ + j0 + h * 32);
    // ---- S = (QK^T)^T for head h=wave: C[m=j][n=i] -> S plane [h][i][j]
    #pragma unroll
    for (int jb = 0; jb < 4; jb++) {
      f32x4 sr = __builtin_amdgcn_mfma_f32_16x16x32_f16(kcur[jb][0], qf[0], zero, 0, 0, 0);
      sr = __builtin_amdgcn_mfma_f32_16x16x32_f16(kcur[jb][1], qf[1], sr, 0, 0, 0);
      f16x4 sv;
      #pragma unroll
      for (int r = 0; r < 4; r++) sv[r] = (_Float16)sr[r];
      *(f16x4*)(Sp + lds_off(wave, l16, jb * 16 + quad * 4)) = sv;
    }
    // ---- prefetch next K tile (kcur dead after the MFMAs above); stays in
    // flight across the raw barriers (no vmcnt drain), consumed in S(t+1).
    if (t < 15) loadK(j0 + 64);
    BARRIER_LDS();
    // ---- mix1 (row i=wave) -> exp (unnormalized) -> P planes + l accumulate
    #pragma unroll
    for (int cg = 0; cg < 4; cg++) {
      f16x4 sf;
      #pragma unroll
      for (int t4 = 0; t4 < 4; t4++)
        sf[t4] = Sp[lds_off(quad * 4 + t4, wave, cg * 16 + l16)];
      f32x4 a = __builtin_amdgcn_mfma_f32_16x16x16f16(sf, w1a, b1i, 0, 0, 0);
      f16x4 pv;
      #pragma unroll
      for (int r = 0; r < 4; r++) {
        float e = __expf(a[r]);
        lacc += e;
        pv[r] = (_Float16)e;
      }
      *(f16x4*)(Pp + lds_off(l16, wave, cg * 16 + quad * 4)) = pv;
    }
    BARRIER_LDS();
    // ---- PV: U_e += V @ P_e^T (e=wave): C[m=d][n=i], V entirely from regs
    f16x8 pf0 = *(const f16x8*)(Pp + lds_off(wave, l16, quad * 8));
    f16x8 pf1 = *(const f16x8*)(Pp + lds_off(wave, l16, 32 + quad * 8));
    #pragma unroll
    for (int nt = 0; nt < 4; nt++)
      uacc[nt] = __builtin_amdgcn_mfma_f32_16x16x32_f16(vreg[0][nt], pf0, uacc[nt], 0, 0, 0);
    #pragma unroll
    for (int nt = 0; nt < 4; nt++)
      uacc[nt] = __builtin_amdgcn_mfma_f32_16x16x32_f16(vreg[1][nt], pf1, uacc[nt], 0, 0, 0);
    // no barrier: next computeS writes S planes (disjoint from P); mix1(t+1)
    // writes P only after the next barrier.
  }

  // ---------------- epilogue ----------------
  // lacc holds partial l for (e=l16, i=wave); reduce over quad (rows j)
  lacc += __shfl_xor(lacc, 16);
  lacc += __shfl_xor(lacc, 32);
  __syncthreads();                       // all PV reads of P done
  if (quad == 0) lsum[l16 * 17 + wave] = lacc;
  __syncthreads();
  float invl = 1.0f / lsum[wave * 17 + l16];   // (e=wave, i=l16)

  // write normalized U planes: Uf[e][i][d], plane stride 1092 (conflict-free)
  _Float16* Uf = Sp;
  #pragma unroll
  for (int nt = 0; nt < 4; nt++) {
    f16x4 u;
    #pragma unroll
    for (int r = 0; r < 4; r++) u[r] = (_Float16)(uacc[nt][r] * invl);
    *(f16x4*)(Uf + wave * 1092 + l16 * 68 + nt * 16 + quad * 4) = u;
  }
  __syncthreads();

  // mix2: O[g][(i,d)] = sum_e W2[g,e] Un[e][(i,d)]; wave = i, 4 d-chunks
  f16x4 w2a = *(const f16x4*)(w2f + l16 * 16 + quad * 4);
  #pragma unroll
  for (int cg = 0; cg < 4; cg++) {
    f16x4 af;
    #pragma unroll
    for (int t4 = 0; t4 < 4; t4++)
      af[t4] = Uf[(quad * 4 + t4) * 1092 + wave * 68 + cg * 16 + l16];
    f32x4 o = __builtin_amdgcn_mfma_f32_16x16x16f16(af, w2a, zero, 0, 0, 0);
    // D: col=l16 -> g, row=quad*4+r -> d = cg*16+quad*4+r (i = wave)
    f32x4 bs = *(const f32x4*)(bsum + b * D_ + l16 * 64 + cg * 16 + quad * 4);
    f16x4 ov;
    #pragma unroll
    for (int r = 0; r < 4; r++) ov[r] = (_Float16)(o[r] + bs[r]);
    *(f16x4*)(ob + (bN + i0 + wave) * D_ + l16 * 64 + cg * 16 + quad * 4) = ov;
  }
}

// ---------------------------------------------------------------------------
extern "C" void kernel_launch(void* const* d_in, const int* in_sizes, int n_in,
                              void* d_out, int out_size, void* d_ws, size_t ws_size,
                              hipStream_t stream) {
  const float* x      = (const float*)d_in[0];
  const float* ln1_w  = (const float*)d_in[1];
  const float* ln1_b  = (const float*)d_in[2];
  const float* qkv_w  = (const float*)d_in[3];
  const float* qkv_b  = (const float*)d_in[4];
  const float* plw    = (const float*)d_in[5];
  const float* plb    = (const float*)d_in[6];
  const float* pww    = (const float*)d_in[7];
  const float* pwb    = (const float*)d_in[8];
  const float* out_w  = (const float*)d_in[9];
  const float* out_b  = (const float*)d_in[10];
  const float* gamma1 = (const float*)d_in[11];
  const float* ln2_w  = (const float*)d_in[12];
  const float* ln2_b  = (const float*)d_in[13];
  const float* fc1_w  = (const float*)d_in[14];
  const float* fc1_b  = (const float*)d_in[15];
  const float* fc2_w  = (const float*)d_in[16];
  const float* fc2_b  = (const float*)d_in[17];
  const float* gamma2 = (const float*)d_in[18];
  float* out = (float*)d_out;

  char* ws = (char*)d_ws;
  _Float16* wq   = (_Float16*)(ws + 0);          // 6291456 B
  _Float16* wo   = (_Float16*)(ws + 6291456);    // 2097152 B
  _Float16* wf1  = (_Float16*)(ws + 8388608);    // 8388608 B (hosts mix tables during attn)
  _Float16* wf2  = (_Float16*)(ws + 16777216);   // 8388608 B
  float*    x1   = (float*)   (ws + 25165824);   // 16777216 B
  _Float16* ob   = (_Float16*)(ws + 41943040);   // 8388608 B
  _Float16* hb   = (_Float16*)(ws + 50331648);   // 8388608 B
  _Float16* qkvb = (_Float16*)(ws + 58720256);   // 25165824 B
  _Float16* vtb  = (_Float16*)(ws + 83886080);   // 8388608 B
  _Float16* fb   = (_Float16*)(ws + 58720256);   // 33554432 B, aliases qkvb+vtb (dead by then)
  _Float16* w1f  = (_Float16*)(ws + 8388608);          // 512 B
  _Float16* w2f  = (_Float16*)(ws + 8388608 + 512);    // 512 B
  float*    bsum = (float*)   (ws + 8388608 + 1024);   // 16384 B
  if (ws_size < 92274688) return;

  cast_f32_f16<<<3072 * 1024 / 1024, 256, 0, stream>>>(qkv_w, wq, 3072 * 1024);
  cast_f32_f16<<<1024 * 1024 / 1024, 256, 0, stream>>>(out_w, wo, 1024 * 1024);
  prep_w<<<1, 256, 0, stream>>>(plw, pww, w1f, w2f);

  ln_f16<<<4096, 256, 0, stream>>>(x, ln1_w, ln1_b, hb);
  gemm_nt<0, 128, 3><<<dim3(24, 32), 256, 0, stream>>>(hb, wq, qkv_b, M_, 3 * D_, D_, qkvb, nullptr, nullptr, nullptr);
  transpose_v<<<dim3(16, 16, 4), 256, 0, stream>>>(qkvb, vtb);
  vsum_k<<<dim3(16, 4), 256, 0, stream>>>(vtb, pwb, bsum);
  attn_th<<<256, 1024, 0, stream>>>(qkvb, vtb, w1f, w2f, plb, bsum, ob);
  gemm_nt<1, 64, 4><<<dim3(16, 32), 256, 0, stream>>>(ob, wo, out_b, M_, D_, D_, nullptr, x1, x, gamma1);

  cast_f32_f16<<<4096 * 1024 / 1024, 256, 0, stream>>>(fc1_w, wf1, 4096 * 1024);
  cast_f32_f16<<<4096 * 1024 / 1024, 256, 0, stream>>>(fc2_w, wf2, 4096 * 1024);

  ln_f16<<<4096, 256, 0, stream>>>(x1, ln2_w, ln2_b, hb);
  gemm_nt<2, 128, 3><<<dim3(32, 32), 256, 0, stream>>>(hb, wf1, fc1_b, M_, FF_, D_, fb, nullptr, nullptr, nullptr);
  gemm_nt<1, 64, 4><<<dim3(16, 32), 256, 0, stream>>>(fb, wf2, fc2_b, M_, D_, FF_, nullptr, out, x1, gamma2);
}

// Round 3
// 463.046 us; speedup vs baseline: 1.0999x; 1.0594x over previous
//
#include <hip/hip_runtime.h>

// ---------------------------------------------------------------------------
// SelfAttentionLayer (talking-heads) on MI355X gfx950. Round 9.
//   * attn_th reverted to round-6 version (best measured: 131 us).
//   * qkv-GEMM and fc1-GEMM ported to the verified 256x256 8-phase schedule
//     (T1 XCD swizzle + T2 LDS XOR swizzle + T3/T4 counted vmcnt + T5 setprio):
//     BK=64, 8 waves, 128KiB double-buffered LDS, 1 half-tile staged per phase,
//     vmcnt(4) only at phases 4/8, lgkmcnt(0)-after-barrier, 16 MFMA/phase.
//   * out-proj / fc2 (N=1024) remain on the 128-tile gemm_nt (grid 64 at 256^2
//     would underfill the machine).
// ---------------------------------------------------------------------------

typedef _Float16 f16x8 __attribute__((ext_vector_type(8)));
typedef _Float16 f16x4 __attribute__((ext_vector_type(4)));
typedef _Float16 f16x2 __attribute__((ext_vector_type(2)));
typedef float f32x4 __attribute__((ext_vector_type(4)));

#define B_ 4
#define N_ 1024
#define D_ 1024
#define H_ 16
#define DH_ 64
#define FF_ 4096
#define M_ (B_ * N_)

__device__ __forceinline__ float gelu_act(float x) {
  float z = 0.7978845608028654f * (x + 0.044715f * x * x * x);
  return x / (1.0f + __expf(-2.0f * z));
}

__device__ __forceinline__ void ld_lds16(const _Float16* g, _Float16* l) {
  __builtin_amdgcn_global_load_lds((const __attribute__((address_space(1))) void*)g,
                                   (__attribute__((address_space(3))) void*)l, 16, 0, 0);
}

__device__ __forceinline__ int swz8(int i) {
  return (((i >> 2) << 1) ^ (i & 3)) & 7;
}
// S/P plane addressing (v4/v5-proven): plane p stride 1032 f16, row i (64 f16),
// col j chunk-swizzled. mix1 u16 gathers, b64 writes, b128 PV reads <=2-way.
__device__ __forceinline__ int lds_off(int p, int i, int j) {
  int ch = ((j >> 3) ^ swz8(i) ^ ((p >> 2) << 1)) & 7;
  return p * 1032 + i * 64 + (ch << 3) + (j & 7);
}

// ---------------- fp32 -> fp16 cast (weights) ----------------
__global__ __launch_bounds__(256) void cast_f32_f16(const float* __restrict__ in,
                                                    _Float16* __restrict__ out, int n) {
  int i = (blockIdx.x * 256 + threadIdx.x) * 4;
  if (i >= n) return;
  float4 v = *(const float4*)(in + i);
  f16x4 o;
  o[0] = (_Float16)v.x; o[1] = (_Float16)v.y; o[2] = (_Float16)v.z; o[3] = (_Float16)v.w;
  *(f16x4*)(out + i) = o;
}

// ---------------- prep mix weights: f16 row-major copies ----------------
__global__ __launch_bounds__(256) void prep_w(const float* __restrict__ W1,
                                              const float* __restrict__ W2,
                                              _Float16* __restrict__ w1f,
                                              _Float16* __restrict__ w2f) {
  int t = threadIdx.x;
  w1f[t] = (_Float16)W1[t];
  w2f[t] = (_Float16)W2[t];
}

// ---------------- bsum[b][g*64+d] = b2[g] * sum_j V[b,g,j,d] ----------------
__global__ __launch_bounds__(256) void vsum_k(const _Float16* __restrict__ vt,
                                              const float* __restrict__ b2,
                                              float* __restrict__ bsum) {
  int g = blockIdx.x, b = blockIdx.y;
  int t = threadIdx.x;
  int d = t >> 2, seg = t & 3;
  const _Float16* row = vt + (size_t)((b * H_ + g) * DH_ + d) * N_ + seg * 256;
  float s = 0.f;
  #pragma unroll
  for (int k = 0; k < 32; k++) {
    f16x8 v = *(const f16x8*)(row + k * 8);
    #pragma unroll
    for (int e = 0; e < 8; e++) s += (float)v[e];
  }
  s += __shfl_xor(s, 1);
  s += __shfl_xor(s, 2);
  if (seg == 0) bsum[b * D_ + g * 64 + d] = b2[g] * s;
}

// ---------------- LayerNorm (row of 1024) -> fp16 ----------------
__global__ __launch_bounds__(256) void ln_f16(const float* __restrict__ x,
                                              const float* __restrict__ w,
                                              const float* __restrict__ b,
                                              _Float16* __restrict__ out) {
  int row = blockIdx.x;
  int tid = threadIdx.x;
  const float* xr = x + (size_t)row * D_;
  float4 v = *(const float4*)(xr + tid * 4);
  float s = v.x + v.y + v.z + v.w;
  float sq = v.x * v.x + v.y * v.y + v.z * v.z + v.w * v.w;
  #pragma unroll
  for (int off = 32; off > 0; off >>= 1) {
    s += __shfl_down(s, off);
    sq += __shfl_down(sq, off);
  }
  __shared__ float red[8];
  int wave = tid >> 6, lane = tid & 63;
  if (lane == 0) { red[wave] = s; red[4 + wave] = sq; }
  __syncthreads();
  float ts = red[0] + red[1] + red[2] + red[3];
  float tq = red[4] + red[5] + red[6] + red[7];
  float mean = ts * (1.0f / (float)D_);
  float var = tq * (1.0f / (float)D_) - mean * mean;
  float rs = rsqrtf(var + 1e-5f);
  float4 wv = *(const float4*)(w + tid * 4);
  float4 bv = *(const float4*)(b + tid * 4);
  f16x4 o;
  o[0] = (_Float16)((v.x - mean) * rs * wv.x + bv.x);
  o[1] = (_Float16)((v.y - mean) * rs * wv.y + bv.y);
  o[2] = (_Float16)((v.z - mean) * rs * wv.z + bv.z);
  o[3] = (_Float16)((v.w - mean) * rs * wv.w + bv.w);
  *(f16x4*)(out + (size_t)row * D_ + tid * 4) = o;
}

// ---------------- NT GEMM (128-tile, 2-barrier): for N=1024 shapes ----------------
template <int EPI, int BN, int OCC>
__global__ __launch_bounds__(256, OCC) void gemm_nt(
    const _Float16* __restrict__ A, const _Float16* __restrict__ W,
    const float* __restrict__ bias, int M, int N, int K,
    _Float16* __restrict__ outB, float* __restrict__ outF,
    const float* __restrict__ res, const float* __restrict__ gamma) {
  __shared__ _Float16 As[128 * 64];
  __shared__ _Float16 Bs[BN * 64];
  int tid = threadIdx.x;
  int wave = tid >> 6, lane = tid & 63;
  int quad = lane >> 4, l16 = lane & 15;
  int wm = wave >> 1, wn = wave & 1;
  int m0 = blockIdx.y * 128, n0 = blockIdx.x * BN;
  int lrow = lane >> 3, lcol = (lane & 7) * 8;
  const int NI = (BN == 128) ? 4 : 2;
  const int WN = (BN == 128) ? 64 : 32;

  f32x4 zero = {0.f, 0.f, 0.f, 0.f};
  f32x4 acc[4][NI];
  #pragma unroll
  for (int i = 0; i < 4; i++)
    #pragma unroll
    for (int j = 0; j < NI; j++) acc[i][j] = zero;

  for (int k0 = 0; k0 < K; k0 += 64) {
    __syncthreads();
    #pragma unroll
    for (int c = 0; c < 4; c++) {
      int rb = c * 32 + wave * 8;
      ld_lds16(A + (size_t)(m0 + rb + lrow) * K + k0 + lcol, As + rb * 64);
      if (BN == 128 || c < 2)
        ld_lds16(W + (size_t)(n0 + rb + lrow) * K + k0 + lcol, Bs + rb * 64);
    }
    __syncthreads();
    #pragma unroll
    for (int ks = 0; ks < 2; ks++) {
      int kk = ks * 32 + quad * 8;
      f16x8 a[4], bfr[NI];
      #pragma unroll
      for (int i = 0; i < 4; i++) a[i] = *(const f16x8*)(As + (wm * 64 + i * 16 + l16) * 64 + kk);
      #pragma unroll
      for (int i = 0; i < NI; i++) bfr[i] = *(const f16x8*)(Bs + (wn * WN + i * 16 + l16) * 64 + kk);
      #pragma unroll
      for (int mi = 0; mi < 4; mi++)
        #pragma unroll
        for (int ni = 0; ni < NI; ni++)
          acc[mi][ni] = __builtin_amdgcn_mfma_f32_16x16x32_f16(a[mi], bfr[ni], acc[mi][ni], 0, 0, 0);
    }
  }

  #pragma unroll
  for (int mi = 0; mi < 4; mi++) {
    int grow_base = m0 + wm * 64 + mi * 16 + quad * 4;
    #pragma unroll
    for (int ni = 0; ni < NI; ni++) {
      int gcol = n0 + wn * WN + ni * 16 + l16;
      float bb = bias[gcol];
      float gm = (EPI == 1) ? gamma[gcol] : 0.f;
      #pragma unroll
      for (int r = 0; r < 4; r++) {
        size_t oi = (size_t)(grow_base + r) * N + gcol;
        float c = acc[mi][ni][r] + bb;
        if (EPI == 0) {
          outB[oi] = (_Float16)c;
        } else if (EPI == 1) {
          outF[oi] = res[oi] + gm * c;
        } else {
          outB[oi] = (_Float16)gelu_act(c);
        }
      }
    }
  }
}

// ---------------- 8-phase 256x256 NT GEMM (K=1024, M,N % 256 == 0) ----------------
// Verified-template port: 8 waves (2M x 4N), per-wave 128x64 out, BK=64,
// LDS [buf][A/B][half][128*64] = 128 KiB. Swizzle: physical chunk =
// logical ^ (row&7), pre-applied to the global source (linear gload_lds dest),
// applied on ds_read_b128. One half-tile (2 loads/thread) staged per phase;
// vmcnt(4) only at phases 4/8 (2 half-tiles in flight past each checkpoint).
#define GPH_OPEN()                                      \
  __builtin_amdgcn_sched_barrier(0);                    \
  __builtin_amdgcn_s_barrier();                         \
  asm volatile("s_waitcnt lgkmcnt(0)" ::: "memory");    \
  __builtin_amdgcn_sched_barrier(0);                    \
  __builtin_amdgcn_s_setprio(1)

#define GPH_CLOSE()                                     \
  __builtin_amdgcn_s_setprio(0);                        \
  __builtin_amdgcn_sched_barrier(0);                    \
  __builtin_amdgcn_s_barrier()

#define GPH_CLOSE_VM(n)                                 \
  __builtin_amdgcn_s_setprio(0);                        \
  __builtin_amdgcn_sched_barrier(0);                    \
  asm volatile("s_waitcnt vmcnt(" #n ")" ::: "memory"); \
  __builtin_amdgcn_s_barrier()

#define GMFMA(MB, NB)                                                         \
  _Pragma("unroll") for (int ks = 0; ks < 2; ks++)                            \
  _Pragma("unroll") for (int mi = 0; mi < 4; mi++)                            \
  _Pragma("unroll") for (int ni = 0; ni < 2; ni++)                            \
    acc[MB + mi][NB + ni] = __builtin_amdgcn_mfma_f32_16x16x32_f16(           \
        ar[mi][ks], br[NB + ni][ks], acc[MB + mi][NB + ni], 0, 0, 0)

#define LDA(buf, MB)                                            \
  _Pragma("unroll") for (int ks = 0; ks < 2; ks++)              \
  _Pragma("unroll") for (int mi = 0; mi < 4; mi++)              \
    ar[mi][ks] = rdf(&lds[buf][0][wm][0], MB + mi, ks)

#define LDB(buf, NB)                                            \
  _Pragma("unroll") for (int ks = 0; ks < 2; ks++)              \
  _Pragma("unroll") for (int ni = 0; ni < 2; ni++)              \
    br[NB + ni][ks] = rdf(&lds[buf][1][wn >> 1][0], fbB + NB + ni, ks)

template <int EPI>
__global__ __launch_bounds__(512, 2) void gemm_nt8(
    const _Float16* __restrict__ A, const _Float16* __restrict__ W,
    const float* __restrict__ bias, int M, int N, int K,
    _Float16* __restrict__ outB) {
  __shared__ _Float16 lds[2][2][2][8192];  // [buf][A=0/B=1][row-half][128*64]
  const int tid = threadIdx.x;
  const int wv = tid >> 6, lane = tid & 63;
  const int quad = lane >> 4, l16 = lane & 15;
  const int wm = wv >> 2, wn = wv & 3;
  const int fbB = (wn & 1) * 4;
  // bijective XCD swizzle (gridDim.x % 8 == 0): XCD x owns a contiguous chunk
  const int wg = ((int)blockIdx.x & 7) * ((int)gridDim.x >> 3) + ((int)blockIdx.x >> 3);
  const int m0 = (wg & 15) << 8;   // M/256 == 16 for all uses here
  const int n0 = (wg >> 4) << 8;
  // staging: thread covers rows srow & srow+64 of a half-tile, 16B chunk
  // pc = lane&7, holding global chunk gc = pc ^ (row&7), row&7 = lane>>3.
  const int gc = ((lane & 7) ^ (lane >> 3)) << 3;
  const int srow = wv * 8 + (lane >> 3);

  auto stageA = [&](int kt, int h) {
    const _Float16* g = A + (size_t)(m0 + h * 128 + srow) * K + kt * 64 + gc;
    _Float16* l = &lds[kt & 1][0][h][wv * 512];
    ld_lds16(g, l);
    ld_lds16(g + (size_t)64 * K, l + 4096);
  };
  auto stageB = [&](int kt, int h) {
    const _Float16* g = W + (size_t)(n0 + h * 128 + srow) * K + kt * 64 + gc;
    _Float16* l = &lds[kt & 1][1][h][wv * 512];
    ld_lds16(g, l);
    ld_lds16(g + (size_t)64 * K, l + 4096);
  };
  // ds_read of fragment (fi, ks): row = fi*16+l16, physical chunk = c^(row&7)
  auto rdf = [&](const _Float16* base, int fi, int ks) -> f16x8 {
    int row = fi * 16 + l16;
    int pc = ((ks << 2) + quad) ^ (l16 & 7);
    return *(const f16x8*)(base + row * 64 + (pc << 3));
  };

  f32x4 acc[8][4];
  const f32x4 zero = {0.f, 0.f, 0.f, 0.f};
  #pragma unroll
  for (int i = 0; i < 8; i++)
    #pragma unroll
    for (int j = 0; j < 4; j++) acc[i][j] = zero;
  f16x8 ar[4][2], br[4][2];

  // prologue: tile0 (A+B) + tile1 (B); A(tile1) staged at Ph1/Ph2.
  stageA(0, 0); stageA(0, 1); stageB(0, 0); stageB(0, 1);
  stageB(1, 0); stageB(1, 1);
  asm volatile("s_waitcnt vmcnt(4)" ::: "memory");
  __builtin_amdgcn_s_barrier();

  const int NT = K >> 6;        // 16
  const int ITERS = NT >> 1;    // 8
  for (int it = 0; it < ITERS - 1; ++it) {
    const int t0 = it * 2;
    // Ph1: t0 q0
    LDA(0, 0); LDB(0, 0); stageA(t0 + 1, 0);
    GPH_OPEN(); GMFMA(0, 0); GPH_CLOSE();
    // Ph2: t0 q1
    LDB(0, 2); stageA(t0 + 1, 1);
    GPH_OPEN(); GMFMA(0, 2); GPH_CLOSE();
    // Ph3: t0 q2  (B(buf0) free after Ph2)
    LDA(0, 4); stageB(t0 + 2, 0);
    GPH_OPEN(); GMFMA(4, 0); GPH_CLOSE();
    // Ph4: t0 q3  (wait: A(t0+1) resident; leave B(t0+2) in flight)
    stageB(t0 + 2, 1);
    GPH_OPEN(); GMFMA(4, 2); GPH_CLOSE_VM(4);
    // Ph5: t1 q0  (A(buf0) free after Ph3)
    LDA(1, 0); LDB(1, 0); stageA(t0 + 2, 0);
    GPH_OPEN(); GMFMA(0, 0); GPH_CLOSE();
    // Ph6: t1 q1
    LDB(1, 2); stageA(t0 + 2, 1);
    GPH_OPEN(); GMFMA(0, 2); GPH_CLOSE();
    // Ph7: t1 q2  (B(buf1) free after Ph6)
    LDA(1, 4); stageB(t0 + 3, 0);
    GPH_OPEN(); GMFMA(4, 0); GPH_CLOSE();
    // Ph8: t1 q3  (wait: A(t0+2) resident; leave B(t0+3) in flight)
    stageB(t0 + 3, 1);
    GPH_OPEN(); GMFMA(4, 2); GPH_CLOSE_VM(4);
  }
  {  // final pair (t0 = NT-2): no staging beyond A(NT-1)
    LDA(0, 0); LDB(0, 0); stageA(NT - 1, 0);
    GPH_OPEN(); GMFMA(0, 0); GPH_CLOSE();
    LDB(0, 2); stageA(NT - 1, 1);
    GPH_OPEN(); GMFMA(0, 2); GPH_CLOSE();
    LDA(0, 4);
    GPH_OPEN(); GMFMA(4, 0); GPH_CLOSE();
    GPH_OPEN(); GMFMA(4, 2); GPH_CLOSE_VM(0);
    LDA(1, 0); LDB(1, 0);
    GPH_OPEN(); GMFMA(0, 0); GPH_CLOSE();
    LDB(1, 2);
    GPH_OPEN(); GMFMA(0, 2); GPH_CLOSE();
    LDA(1, 4);
    GPH_OPEN(); GMFMA(4, 0); GPH_CLOSE();
    GPH_OPEN(); GMFMA(4, 2); GPH_CLOSE();
  }

  // epilogue
  #pragma unroll
  for (int mi = 0; mi < 8; mi++) {
    int grow = m0 + wm * 128 + mi * 16 + quad * 4;
    #pragma unroll
    for (int ni = 0; ni < 4; ni++) {
      int gcol = n0 + wn * 64 + ni * 16 + l16;
      float bb = bias[gcol];
      #pragma unroll
      for (int r = 0; r < 4; r++) {
        size_t oi = (size_t)(grow + r) * N + gcol;
        float c = acc[mi][ni][r] + bb;
        outB[oi] = (_Float16)(EPI == 2 ? gelu_act(c) : c);
      }
    }
  }
}

// ---------------- V transpose: vt[b][h][d][j] ----------------
__global__ __launch_bounds__(256) void transpose_v(const _Float16* __restrict__ qkv,
                                                   _Float16* __restrict__ vt) {
  int jt = blockIdx.x;
  int h = blockIdx.y;
  int b = blockIdx.z;
  __shared__ _Float16 tl[64][68];
  int tid = threadIdx.x;
  int j0 = jt * 64;
  #pragma unroll
  for (int k = 0; k < 16; k++) {
    int idx = k * 256 + tid;
    int jr = idx >> 6, dc = idx & 63;
    tl[jr][dc] = qkv[(size_t)(b * N_ + j0 + jr) * (3 * D_) + 2 * D_ + h * 64 + dc];
  }
  __syncthreads();
  #pragma unroll
  for (int k = 0; k < 16; k++) {
    int idx = k * 256 + tid;
    int dr = idx >> 6, jc = idx & 63;
    vt[(size_t)((b * H_ + h) * DH_ + dr) * N_ + j0 + jc] = tl[jc][dr];
  }
}

// ---------------- Talking-heads attention (round-6 version) ----------------
// grid (64 i-tiles, 4 b), 1024 thr = 16 waves. Wave index means:
// computeS: head h=wave; mix1: row i=wave; PV: mixed-head e=wave;
// epilogue mix2/store: row i=wave.
__global__ __launch_bounds__(1024, 4) void attn_th(
    const _Float16* __restrict__ qkv, const _Float16* __restrict__ vt,
    const _Float16* __restrict__ w1f, const _Float16* __restrict__ w2f,
    const float* __restrict__ b1f, const float* __restrict__ bsum,
    _Float16* __restrict__ ob) {
  __shared__ __align__(16) _Float16 SP[2 * 16512];  // S planes | P planes
  __shared__ float lsum[272];                       // [e][i] + pad (stride 17)
  _Float16* Sp = SP;
  _Float16* Pp = SP + 16512;

  const int tid = threadIdx.x;
  const int wave = tid >> 6;
  const int lane = tid & 63;
  const int quad = lane >> 4, l16 = lane & 15;
  const int i0 = blockIdx.x * 16;
  const int b = blockIdx.y;
  const size_t bN = (size_t)b * N_;
  const f32x4 zero = {0.f, 0.f, 0.f, 0.f};

  // Q fragments (head=wave), pre-scaled by DH^-1/2 = 0.125 (exact in f16)
  f16x8 qf[2];
  #pragma unroll
  for (int ks = 0; ks < 2; ks++) {
    f16x8 q = *(const f16x8*)(qkv + (bN + i0 + l16) * 3072 + wave * 64 + ks * 32 + quad * 8);
    #pragma unroll
    for (int e = 0; e < 8; e++) q[e] = q[e] * (_Float16)0.125f;
    qf[ks] = q;
  }
  // W1 B-fragment: B[k=h][n=e] = W1[e][h]
  f16x4 w1a = *(const f16x4*)(w1f + l16 * 16 + quad * 4);
  float b1v = b1f[l16];
  f32x4 b1i = {b1v, b1v, b1v, b1v};

  const _Float16* vbase = vt + (size_t)((b * H_ + wave) * DH_ + l16) * N_ + quad * 8;

  f32x4 uacc[4];
  #pragma unroll
  for (int nt = 0; nt < 4; nt++) uacc[nt] = zero;
  float lacc = 0.f;

  // K fragments for the current tile (reloaded in place each iteration)
  f16x8 kcur[4][2];
  auto loadK = [&](int j0) {
    #pragma unroll
    for (int jb = 0; jb < 4; jb++) {
      const _Float16* kb = qkv + (bN + j0 + jb * 16 + l16) * 3072 + 1024 + wave * 64 + quad * 8;
      kcur[jb][0] = *(const f16x8*)kb;
      kcur[jb][1] = *(const f16x8*)(kb + 32);
    }
  };
  loadK(0);

  f16x8 vreg[4];  // first 32-j half of V tile, prefetched

  for (int t = 0; t < 16; t++) {
    int j0 = t * 64;
    // ---- S = (QK^T)^T for head h=wave: C[m=j][n=i] -> S plane [h][i][j]
    f32x4 sres[4];
    #pragma unroll
    for (int jb = 0; jb < 4; jb++) {
      f32x4 s = __builtin_amdgcn_mfma_f32_16x16x32_f16(kcur[jb][0], qf[0], zero, 0, 0, 0);
      sres[jb] = __builtin_amdgcn_mfma_f32_16x16x32_f16(kcur[jb][1], qf[1], s, 0, 0, 0);
    }
    #pragma unroll
    for (int jb = 0; jb < 4; jb++) {
      f16x4 sv;
      #pragma unroll
      for (int r = 0; r < 4; r++) sv[r] = (_Float16)sres[jb][r];
      *(f16x4*)(Sp + lds_off(wave, l16, jb * 16 + quad * 4)) = sv;
    }
    // ---- prefetch next K tile (kcur dead after the MFMAs above) and this
    // tile's first V half; the barrier's vmcnt(0) drain makes them resident.
    if (t < 15) loadK(j0 + 64);
    #pragma unroll
    for (int nt = 0; nt < 4; nt++)
      vreg[nt] = *(const f16x8*)(vbase + (size_t)(nt * 16) * N_ + j0);
    __syncthreads();
    // ---- mix1 (row i=wave) -> exp (unnormalized) -> P planes + l accumulate
    #pragma unroll
    for (int cg = 0; cg < 4; cg++) {
      f16x4 sf;
      #pragma unroll
      for (int t4 = 0; t4 < 4; t4++)
        sf[t4] = Sp[lds_off(quad * 4 + t4, wave, cg * 16 + l16)];
      f32x4 a = __builtin_amdgcn_mfma_f32_16x16x16f16(sf, w1a, b1i, 0, 0, 0);
      f16x4 pv;
      #pragma unroll
      for (int r = 0; r < 4; r++) {
        float e = __expf(a[r]);
        lacc += e;
        pv[r] = (_Float16)e;
      }
      *(f16x4*)(Pp + lds_off(l16, wave, cg * 16 + quad * 4)) = pv;
    }
    __syncthreads();
    // ---- PV: U_e += V @ P_e^T (e=wave): C[m=d][n=i]
    f16x8 pf0 = *(const f16x8*)(Pp + lds_off(wave, l16, quad * 8));
    f16x8 pf1 = *(const f16x8*)(Pp + lds_off(wave, l16, 32 + quad * 8));
    #pragma unroll
    for (int nt = 0; nt < 4; nt++)
      uacc[nt] = __builtin_amdgcn_mfma_f32_16x16x32_f16(vreg[nt], pf0, uacc[nt], 0, 0, 0);
    #pragma unroll
    for (int nt = 0; nt < 4; nt++) {
      f16x8 vf = *(const f16x8*)(vbase + (size_t)(nt * 16) * N_ + j0 + 32);
      uacc[nt] = __builtin_amdgcn_mfma_f32_16x16x32_f16(vf, pf1, uacc[nt], 0, 0, 0);
    }
    // no barrier: next computeS writes S planes (disjoint from P); mix1(t+1)
    // writes P only after the next barrier.
  }

  // ---------------- epilogue ----------------
  // lacc holds partial l for (e=l16, i=wave); reduce over quad (rows j)
  lacc += __shfl_xor(lacc, 16);
  lacc += __shfl_xor(lacc, 32);
  __syncthreads();                       // all PV reads of P done
  if (quad == 0) lsum[l16 * 17 + wave] = lacc;
  __syncthreads();
  float invl = 1.0f / lsum[wave * 17 + l16];   // (e=wave, i=l16)

  // write normalized U planes: Uf[e][i][d], plane stride 1092 (conflict-free)
  _Float16* Uf = Sp;
  #pragma unroll
  for (int nt = 0; nt < 4; nt++) {
    f16x4 u;
    #pragma unroll
    for (int r = 0; r < 4; r++) u[r] = (_Float16)(uacc[nt][r] * invl);
    *(f16x4*)(Uf + wave * 1092 + l16 * 68 + nt * 16 + quad * 4) = u;
  }
  __syncthreads();

  // mix2: O[g][(i,d)] = sum_e W2[g,e] Un[e][(i,d)]; wave = i, 4 d-chunks
  f16x4 w2a = *(const f16x4*)(w2f + l16 * 16 + quad * 4);
  #pragma unroll
  for (int cg = 0; cg < 4; cg++) {
    f16x4 af;
    #pragma unroll
    for (int t4 = 0; t4 < 4; t4++)
      af[t4] = Uf[(quad * 4 + t4) * 1092 + wave * 68 + cg * 16 + l16];
    f32x4 o = __builtin_amdgcn_mfma_f32_16x16x16f16(af, w2a, zero, 0, 0, 0);
    // D: col=l16 -> g, row=quad*4+r -> d = cg*16+quad*4+r (i = wave)
    f32x4 bs = *(const f32x4*)(bsum + b * D_ + l16 * 64 + cg * 16 + quad * 4);
    f16x4 ov;
    #pragma unroll
    for (int r = 0; r < 4; r++) ov[r] = (_Float16)(o[r] + bs[r]);
    *(f16x4*)(ob + (bN + i0 + wave) * D_ + l16 * 64 + cg * 16 + quad * 4) = ov;
  }
}

// ---------------------------------------------------------------------------
extern "C" void kernel_launch(void* const* d_in, const int* in_sizes, int n_in,
                              void* d_out, int out_size, void* d_ws, size_t ws_size,
                              hipStream_t stream) {
  const float* x      = (const float*)d_in[0];
  const float* ln1_w  = (const float*)d_in[1];
  const float* ln1_b  = (const float*)d_in[2];
  const float* qkv_w  = (const float*)d_in[3];
  const float* qkv_b  = (const float*)d_in[4];
  const float* plw    = (const float*)d_in[5];
  const float* plb    = (const float*)d_in[6];
  const float* pww    = (const float*)d_in[7];
  const float* pwb    = (const float*)d_in[8];
  const float* out_w  = (const float*)d_in[9];
  const float* out_b  = (const float*)d_in[10];
  const float* gamma1 = (const float*)d_in[11];
  const float* ln2_w  = (const float*)d_in[12];
  const float* ln2_b  = (const float*)d_in[13];
  const float* fc1_w  = (const float*)d_in[14];
  const float* fc1_b  = (const float*)d_in[15];
  const float* fc2_w  = (const float*)d_in[16];
  const float* fc2_b  = (const float*)d_in[17];
  const float* gamma2 = (const float*)d_in[18];
  float* out = (float*)d_out;

  char* ws = (char*)d_ws;
  _Float16* wq   = (_Float16*)(ws + 0);          // 6291456 B
  _Float16* wo   = (_Float16*)(ws + 6291456);    // 2097152 B
  _Float16* wf1  = (_Float16*)(ws + 8388608);    // 8388608 B (hosts mix tables during attn)
  _Float16* wf2  = (_Float16*)(ws + 16777216);   // 8388608 B
  float*    x1   = (float*)   (ws + 25165824);   // 16777216 B
  _Float16* ob   = (_Float16*)(ws + 41943040);   // 8388608 B
  _Float16* hb   = (_Float16*)(ws + 50331648);   // 8388608 B
  _Float16* qkvb = (_Float16*)(ws + 58720256);   // 25165824 B
  _Float16* vtb  = (_Float16*)(ws + 83886080);   // 8388608 B
  _Float16* fb   = (_Float16*)(ws + 58720256);   // 33554432 B, aliases qkvb+vtb (dead by then)
  _Float16* w1f  = (_Float16*)(ws + 8388608);          // 512 B
  _Float16* w2f  = (_Float16*)(ws + 8388608 + 512);    // 512 B
  float*    bsum = (float*)   (ws + 8388608 + 1024);   // 16384 B
  if (ws_size < 92274688) return;

  cast_f32_f16<<<3072 * 1024 / 1024, 256, 0, stream>>>(qkv_w, wq, 3072 * 1024);
  cast_f32_f16<<<1024 * 1024 / 1024, 256, 0, stream>>>(out_w, wo, 1024 * 1024);
  prep_w<<<1, 256, 0, stream>>>(plw, pww, w1f, w2f);

  ln_f16<<<4096, 256, 0, stream>>>(x, ln1_w, ln1_b, hb);
  gemm_nt8<0><<<192, 512, 0, stream>>>(hb, wq, qkv_b, M_, 3 * D_, D_, qkvb);
  transpose_v<<<dim3(16, 16, 4), 256, 0, stream>>>(qkvb, vtb);
  vsum_k<<<dim3(16, 4), 256, 0, stream>>>(vtb, pwb, bsum);
  attn_th<<<dim3(64, 4), 1024, 0, stream>>>(qkvb, vtb, w1f, w2f, plb, bsum, ob);
  gemm_nt<1, 64, 4><<<dim3(16, 32), 256, 0, stream>>>(ob, wo, out_b, M_, D_, D_, nullptr, x1, x, gamma1);

  cast_f32_f16<<<4096 * 1024 / 1024, 256, 0, stream>>>(fc1_w, wf1, 4096 * 1024);
  cast_f32_f16<<<4096 * 1024 / 1024, 256, 0, stream>>>(fc2_w, wf2, 4096 * 1024);

  ln_f16<<<4096, 256, 0, stream>>>(x1, ln2_w, ln2_b, hb);
  gemm_nt8<2><<<256, 512, 0, stream>>>(hb, wf1, fc1_b, M_, FF_, D_, fb);
  gemm_nt<1, 64, 4><<<dim3(16, 32), 256, 0, stream>>>(fb, wf2, fc2_b, M_, D_, FF_, nullptr, out, x1, gamma2);
}